// Round 1
// baseline (231.479 us; speedup 1.0000x reference)
//
#include <hip/hip_runtime.h>

#define NTOK   2048
#define DIM    512
#define FDIM   2048
#define NEXP   16
#define CAP    768     // max routed tokens buffered per expert (mean ~256)
#define BT     256     // token block per K2 pass

typedef __bf16 bf16x8 __attribute__((ext_vector_type(8)));
typedef __bf16 bf16x4 __attribute__((ext_vector_type(4)));
typedef float  floatx4 __attribute__((ext_vector_type(4)));

// workspace layout (bytes)
#define WS_COUNTS    0         // 16 ints (memset 0)
#define WS_ZEROPAGE  1024      // >=16B zeros for pad-lane loads (memset 0)
#define WS_TOPIDX    4096      // NTOK*2 ints
#define WS_ROUTW     20480     // NTOK*2 floats
#define WS_HMEAN     36864     // NEXP*FDIM floats
#define WS_YMEAN     167936    // NEXP*DIM floats
#define WS_XG        200704    // NEXP*CAP*DIM bf16 = 12.6 MB

// ---------------- K1: gate logits, top-2 softmax, gather x rows (bf16) ------
__global__ __launch_bounds__(256) void k1_route_gather(
    const float* __restrict__ x, const float* __restrict__ gw,
    int* __restrict__ counts, int* __restrict__ top_idx,
    float* __restrict__ routw, __bf16* __restrict__ Xg)
{
    __shared__ float xt[16 * DIM];    // 32 KB: 16 token rows
    __shared__ float lg[16][17];
    __shared__ int   gdst[16][2];
    const int tid = threadIdx.x;
    const int t0  = blockIdx.x * 16;

    {   // stage 16 token rows, coalesced float4
        const float4* src = (const float4*)(x + (size_t)t0 * DIM);
        float4* dst = (float4*)xt;
        #pragma unroll
        for (int i = 0; i < 8; ++i) dst[i * 256 + tid] = src[i * 256 + tid];
    }
    __syncthreads();

    {   // logits: thread = (token tl, expert e)
        const int tl = tid >> 4, e = tid & 15;
        const float4* xr = (const float4*)(xt + tl * DIM);
        const float4* gr = (const float4*)(gw + e * DIM);
        float acc = 0.f;
        #pragma unroll 8
        for (int j = 0; j < DIM / 4; ++j) {
            float4 a = xr[j], b = gr[j];
            acc += a.x * b.x + a.y * b.y + a.z * b.z + a.w * b.w;
        }
        lg[tl][e] = acc;
    }
    __syncthreads();

    if (tid < 16) {   // per-token top-2 + softmax + slot allocation
        const int tl = tid;
        float v0 = -1e30f, v1 = -1e30f; int i0 = 0, i1 = 0;
        #pragma unroll
        for (int e = 0; e < NEXP; ++e) {
            float v = lg[tl][e];
            if (v > v0)      { v1 = v0; i1 = i0; v0 = v; i0 = e; }
            else if (v > v1) { v1 = v;  i1 = e; }
        }
        float e1 = __expf(v1 - v0);          // v0 >= v1
        float w0 = 1.f / (1.f + e1);
        float w1 = 1.f - w0;
        const int t = t0 + tl;
        top_idx[t * 2]     = i0; top_idx[t * 2 + 1] = i1;
        routw[t * 2]       = w0; routw[t * 2 + 1]   = w1;
        int p0 = atomicAdd(counts + i0, 1);
        int p1 = atomicAdd(counts + i1, 1);
        gdst[tl][0] = (p0 < CAP) ? (i0 * CAP + p0) : -1;
        gdst[tl][1] = (p1 < CAP) ? (i1 * CAP + p1) : -1;
    }
    __syncthreads();

    // gather-write 32 rows (16 tokens x 2 experts) as bf16, 8B stores
    #pragma unroll
    for (int it = 0; it < 16; ++it) {
        int s   = it * 256 + tid;          // 0..4095
        int job = s >> 7, el = s & 127;    // job: (token,k), el: float4 index
        int tl  = job >> 1, k = job & 1;
        int dst = gdst[tl][k];
        if (dst >= 0) {
            float4 v = ((const float4*)(xt + tl * DIM))[el];
            bf16x4 o = { (__bf16)v.x, (__bf16)v.y, (__bf16)v.z, (__bf16)v.w };
            *(bf16x4*)(Xg + (size_t)dst * DIM + el * 4) = o;
        }
    }
}

// ---------------- K2: per (expert, 64-row F-tile): silu(Xg @ W1^T) col-mean --
// grid = 32 f-tiles * 16 experts; block = 256 (4 waves).
// Wave w: f rows [fsub, fsub+32), tokens [tsub, tsub+128) of the 256-token pass.
__global__ __launch_bounds__(256) void k2_expert_ffn(
    const float* __restrict__ w1, const __bf16* __restrict__ Xg,
    const int* __restrict__ counts, const __bf16* __restrict__ zp,
    float* __restrict__ hmean)
{
    __shared__ __align__(16) __bf16 w1s[8 * 65 * 8];    // [kg][f(+pad)][8]
    __shared__ __align__(16) __bf16 xs[8 * 257 * 8];    // [kg][t(+pad)][8]
    __shared__ float hred[64][2];

    const int tid  = threadIdx.x;
    const int bid  = blockIdx.x;
    const int e    = bid & 15;           // expert fast -> 2 experts per XCD
    const int f0   = (bid >> 4) * 64;
    const int cnt  = min(counts[e], CAP);
    const int nblk = (cnt + BT - 1) / BT;
    const float inv = 1.f / (float)max(cnt, 1);

    const int wv   = tid >> 6;
    const int lane = tid & 63;
    const int q    = lane >> 4;          // mfma quad
    const int l15  = lane & 15;
    const int fsub = (wv & 1) * 32;
    const int tsub = (wv >> 1) * 128;

    floatx4 acc[2][8];
    float hs[8];
    #pragma unroll
    for (int a = 0; a < 2; ++a)
        #pragma unroll
        for (int b = 0; b < 8; ++b) acc[a][b] = (floatx4)0.f;
    #pragma unroll
    for (int i = 0; i < 8; ++i) hs[i] = 0.f;

    for (int tb = 0; tb < nblk; ++tb) {
        for (int c = 0; c < 8; ++c) {            // K chunks of 64
            const int d0 = c * 64;
            __syncthreads();
            // stage W1 tile chunk: 64 f x 64 d, fp32 -> bf16
            #pragma unroll
            for (int it = 0; it < 2; ++it) {
                int s = it * 256 + tid;
                int f = s >> 3, g = s & 7;
                const float* src = w1 + ((size_t)(e * FDIM + f0 + f)) * DIM + d0 + g * 8;
                float4 a = ((const float4*)src)[0];
                float4 b = ((const float4*)src)[1];
                bf16x8 v;
                v[0] = (__bf16)a.x; v[1] = (__bf16)a.y; v[2] = (__bf16)a.z; v[3] = (__bf16)a.w;
                v[4] = (__bf16)b.x; v[5] = (__bf16)b.y; v[6] = (__bf16)b.z; v[7] = (__bf16)b.w;
                *(bf16x8*)(w1s + ((size_t)g * 65 + f) * 8) = v;
            }
            // stage X chunk: 256 t x 64 d (bf16 gathered; pads read zero page)
            {
                const int kg = tid & 7;
                const int tb8 = tid >> 3;
                #pragma unroll
                for (int it = 0; it < 8; ++it) {
                    int t = it * 32 + tb8;
                    int r = tb * BT + t;
                    const __bf16* src = (r < cnt)
                        ? (Xg + ((size_t)(e * CAP + r)) * DIM + d0 + kg * 8)
                        : zp;
                    uint4 d = *(const uint4*)src;
                    *(uint4*)(xs + ((size_t)kg * 257 + t) * 8) = d;
                }
            }
            __syncthreads();
            // 2 K-steps of 32 per chunk
            #pragma unroll
            for (int ks = 0; ks < 2; ++ks) {
                const int kg = ks * 4 + q;
                bf16x8 af0 = *(const bf16x8*)(w1s + (kg * 65 + fsub + l15) * 8);
                bf16x8 af1 = *(const bf16x8*)(w1s + (kg * 65 + fsub + 16 + l15) * 8);
                #pragma unroll
                for (int tt = 0; tt < 8; ++tt) {
                    bf16x8 bfr = *(const bf16x8*)(xs + (kg * 257 + tsub + tt * 16 + l15) * 8);
                    acc[0][tt] = __builtin_amdgcn_mfma_f32_16x16x32_bf16(af0, bfr, acc[0][tt], 0, 0, 0);
                    acc[1][tt] = __builtin_amdgcn_mfma_f32_16x16x32_bf16(af1, bfr, acc[1][tt], 0, 0, 0);
                }
            }
        }
        // pass epilogue: silu then accumulate (pad cols give silu(0)=0)
        #pragma unroll
        for (int fa = 0; fa < 2; ++fa)
            #pragma unroll
            for (int tt = 0; tt < 8; ++tt)
                #pragma unroll
                for (int r = 0; r < 4; ++r) {
                    float v = acc[fa][tt][r];
                    hs[fa * 4 + r] += v / (1.f + __expf(-v));
                    acc[fa][tt][r] = 0.f;
                }
    }

    // sum over the 16 token-columns held across lanes of each quad
    #pragma unroll
    for (int i = 0; i < 8; ++i) {
        float v = hs[i];
        v += __shfl_xor(v, 1);
        v += __shfl_xor(v, 2);
        v += __shfl_xor(v, 4);
        v += __shfl_xor(v, 8);
        hs[i] = v;
    }
    if (l15 == 0) {
        #pragma unroll
        for (int fa = 0; fa < 2; ++fa)
            #pragma unroll
            for (int r = 0; r < 4; ++r) {
                int row = fsub + fa * 16 + q * 4 + r;
                hred[row][wv >> 1] = hs[fa * 4 + r];
            }
    }
    __syncthreads();
    if (tid < 64)
        hmean[(size_t)e * FDIM + f0 + tid] = (hred[tid][0] + hred[tid][1]) * inv;
}

// ---------------- K3: y_mean[e,d] = h_mean[e,:] . w2[e,d,:]  (fp32) ---------
__global__ __launch_bounds__(256) void k3_ymean(
    const float* __restrict__ w2, const float* __restrict__ hmean,
    const int* __restrict__ counts, float* __restrict__ ymean)
{
    __shared__ float hl[FDIM];           // 8 KB
    const int tid = threadIdx.x;
    const int bid = blockIdx.x;
    const int e   = bid >> 7;
    const int d0  = (bid & 127) * 4;

    {
        const float4* hg = (const float4*)(hmean + (size_t)e * FDIM);
        float4* hl4 = (float4*)hl;
        hl4[tid]       = hg[tid];
        hl4[256 + tid] = hg[256 + tid];
    }
    __syncthreads();

    const int wv = tid >> 6, lane = tid & 63;
    const int d = d0 + wv;
    const float4* wr  = (const float4*)(w2 + ((size_t)e * DIM + d) * FDIM);
    const float4* hl4 = (const float4*)hl;
    float acc = 0.f;
    #pragma unroll
    for (int i = 0; i < 8; ++i) {
        float4 a = wr[i * 64 + lane];
        float4 h = hl4[i * 64 + lane];
        acc += a.x * h.x + a.y * h.y + a.z * h.z + a.w * h.w;
    }
    #pragma unroll
    for (int m = 1; m < 64; m <<= 1) acc += __shfl_xor(acc, m);
    if (lane == 0)
        ymean[e * DIM + d] = (counts[e] > 0) ? acc : 0.f;
}

// ---------------- K4: out[t,:] = w0*y[e0,:] + w1*y[e1,:] --------------------
__global__ __launch_bounds__(256) void k4_combine(
    const int* __restrict__ top_idx, const float* __restrict__ routw,
    const float* __restrict__ ymean, float* __restrict__ out)
{
    const int idx = blockIdx.x * 256 + threadIdx.x;   // float4 index
    const int t = idx >> 7;
    const int c = idx & 127;
    const int i0 = top_idx[t * 2], i1 = top_idx[t * 2 + 1];
    const float w0 = routw[t * 2], w1 = routw[t * 2 + 1];
    float4 a = ((const float4*)(ymean + (size_t)i0 * DIM))[c];
    float4 b = ((const float4*)(ymean + (size_t)i1 * DIM))[c];
    float4 o;
    o.x = w0 * a.x + w1 * b.x;
    o.y = w0 * a.y + w1 * b.y;
    o.z = w0 * a.z + w1 * b.z;
    o.w = w0 * a.w + w1 * b.w;
    ((float4*)out)[idx] = o;
}

extern "C" void kernel_launch(void* const* d_in, const int* in_sizes, int n_in,
                              void* d_out, int out_size, void* d_ws, size_t ws_size,
                              hipStream_t stream)
{
    (void)in_sizes; (void)n_in; (void)out_size; (void)ws_size;
    const float* x  = (const float*)d_in[0];   // [4,512,512]
    const float* gw = (const float*)d_in[1];   // [16,512]
    const float* w1 = (const float*)d_in[2];   // [16,2048,512]
    const float* w2 = (const float*)d_in[3];   // [16,512,2048]
    float* out = (float*)d_out;

    char* ws = (char*)d_ws;
    int*    counts  = (int*)   (ws + WS_COUNTS);
    const __bf16* zp = (const __bf16*)(ws + WS_ZEROPAGE);
    int*    top_idx = (int*)   (ws + WS_TOPIDX);
    float*  routw   = (float*) (ws + WS_ROUTW);
    float*  hmean   = (float*) (ws + WS_HMEAN);
    float*  ymean   = (float*) (ws + WS_YMEAN);
    __bf16* Xg      = (__bf16*)(ws + WS_XG);

    hipMemsetAsync(d_ws, 0, 4096, stream);   // counts + zero page

    k1_route_gather<<<dim3(NTOK / 16), dim3(256), 0, stream>>>(x, gw, counts, top_idx, routw, Xg);
    k2_expert_ffn  <<<dim3(32 * NEXP), dim3(256), 0, stream>>>(w1, Xg, counts, zp, hmean);
    k3_ymean       <<<dim3(NEXP * 128), dim3(256), 0, stream>>>(w2, hmean, counts, ymean);
    k4_combine     <<<dim3(NTOK * DIM / 4 / 256), dim3(256), 0, stream>>>(top_idx, routw, ymean, out);
}

// Round 2
// 211.063 us; speedup vs baseline: 1.0967x; 1.0967x over previous
//
#include <hip/hip_runtime.h>

#define NTOK   2048
#define DIM    512
#define FDIM   2048
#define NEXP   16
#define CAP    768     // max routed tokens buffered per expert (mean ~256)
#define BT2    128     // token block per K2 workgroup
#define NTB    (CAP / BT2)   // 6 token-block slots

typedef __bf16 bf16x8 __attribute__((ext_vector_type(8)));
typedef __bf16 bf16x4 __attribute__((ext_vector_type(4)));
typedef float  floatx4 __attribute__((ext_vector_type(4)));

// workspace layout (bytes)
#define WS_COUNTS    0         // 16 ints (memset 0)
#define WS_ZEROPAGE  1024      // >=16B zeros for pad-lane loads (memset 0)
#define WS_TOPIDX    4096      // NTOK*2 ints
#define WS_ROUTW     20480     // NTOK*2 floats
#define WS_HMEAN     36864     // NEXP*FDIM floats (memset 0 — atomic accumulated)
#define WS_YMEAN     167936    // NEXP*DIM floats
#define WS_XG        200704    // NEXP*CAP*DIM bf16 = 12.6 MB
#define WS_ZERO_BYTES 167936   // memset covers counts..hmean

// ---------------- K1: gate logits, top-2 softmax, gather x rows (bf16) ------
__global__ __launch_bounds__(256) void k1_route_gather(
    const float* __restrict__ x, const float* __restrict__ gw,
    int* __restrict__ counts, int* __restrict__ top_idx,
    float* __restrict__ routw, __bf16* __restrict__ Xg)
{
    __shared__ float xt[16 * DIM];    // 32 KB: 16 token rows
    __shared__ float lg[16][17];
    __shared__ int   gdst[16][2];
    const int tid = threadIdx.x;
    const int t0  = blockIdx.x * 16;

    {   // stage 16 token rows, coalesced float4
        const float4* src = (const float4*)(x + (size_t)t0 * DIM);
        float4* dst = (float4*)xt;
        #pragma unroll
        for (int i = 0; i < 8; ++i) dst[i * 256 + tid] = src[i * 256 + tid];
    }
    __syncthreads();

    {   // logits: thread = (token tl, expert e)
        const int tl = tid >> 4, e = tid & 15;
        const float4* xr = (const float4*)(xt + tl * DIM);
        const float4* gr = (const float4*)(gw + e * DIM);
        float acc = 0.f;
        #pragma unroll 8
        for (int j = 0; j < DIM / 4; ++j) {
            float4 a = xr[j], b = gr[j];
            acc += a.x * b.x + a.y * b.y + a.z * b.z + a.w * b.w;
        }
        lg[tl][e] = acc;
    }
    __syncthreads();

    if (tid < 16) {   // per-token top-2 + softmax + slot allocation
        const int tl = tid;
        float v0 = -1e30f, v1 = -1e30f; int i0 = 0, i1 = 0;
        #pragma unroll
        for (int e = 0; e < NEXP; ++e) {
            float v = lg[tl][e];
            if (v > v0)      { v1 = v0; i1 = i0; v0 = v; i0 = e; }
            else if (v > v1) { v1 = v;  i1 = e; }
        }
        float e1 = __expf(v1 - v0);          // v0 >= v1
        float w0 = 1.f / (1.f + e1);
        float w1 = 1.f - w0;
        const int t = t0 + tl;
        top_idx[t * 2]     = i0; top_idx[t * 2 + 1] = i1;
        routw[t * 2]       = w0; routw[t * 2 + 1]   = w1;
        int p0 = atomicAdd(counts + i0, 1);
        int p1 = atomicAdd(counts + i1, 1);
        gdst[tl][0] = (p0 < CAP) ? (i0 * CAP + p0) : -1;
        gdst[tl][1] = (p1 < CAP) ? (i1 * CAP + p1) : -1;
    }
    __syncthreads();

    // gather-write 32 rows (16 tokens x 2 experts) as bf16, 8B stores
    #pragma unroll
    for (int it = 0; it < 16; ++it) {
        int s   = it * 256 + tid;          // 0..4095
        int job = s >> 7, el = s & 127;    // job: (token,k), el: float4 index
        int tl  = job >> 1, k = job & 1;
        int dst = gdst[tl][k];
        if (dst >= 0) {
            float4 v = ((const float4*)(xt + tl * DIM))[el];
            bf16x4 o = { (__bf16)v.x, (__bf16)v.y, (__bf16)v.z, (__bf16)v.w };
            *(bf16x4*)(Xg + (size_t)dst * DIM + el * 4) = o;
        }
    }
}

// ---------------- K2: per (expert, 64-f-tile, 128-token-block) --------------
// silu(Xg @ W1^T) column-partial-sums, pre-scaled by 1/cnt, atomicAdd to hmean.
// grid = NTB(slow) x 32 f-tiles x 16 experts(fast); block = 256 (4 waves).
// Wave w: f rows [fsub,fsub+32), tokens [tsub,tsub+64) of the 128-token block.
__global__ __launch_bounds__(256) void k2_expert_ffn(
    const float* __restrict__ w1, const __bf16* __restrict__ Xg,
    const int* __restrict__ counts, const __bf16* __restrict__ zp,
    float* __restrict__ hmean)
{
    __shared__ __align__(16) __bf16 w1s[8 * 65 * 8];    // 8.3 KB [kg][f(+pad)][8]
    __shared__ __align__(16) __bf16 xs[8 * 129 * 8];    // 16.5 KB [kg][t(+pad)][8]
    __shared__ float hred[64][2];

    const int tid = threadIdx.x;
    const int bid = blockIdx.x;
    const int tb  = bid >> 9;            // slow: token-block (same (e,f) tiles 512 apart -> same XCD)
    const int rem = bid & 511;
    const int e   = rem & 15;            // expert fast
    const int f0  = (rem >> 4) * 64;
    const int cnt = min(counts[e], CAP);
    if (tb * BT2 >= cnt) return;         // inactive slot
    const float inv = 1.f / (float)cnt;

    const int wv   = tid >> 6;
    const int lane = tid & 63;
    const int q    = lane >> 4;          // mfma quad
    const int l15  = lane & 15;
    const int fsub = (wv & 1) * 32;
    const int tsub = (wv >> 1) * 64;

    floatx4 acc[2][4];
    #pragma unroll
    for (int a = 0; a < 2; ++a)
        #pragma unroll
        for (int b = 0; b < 4; ++b) acc[a][b] = (floatx4)0.f;

    for (int c = 0; c < 8; ++c) {        // K chunks of 64
        const int d0 = c * 64;
        __syncthreads();
        // stage W1 tile chunk: 64 f x 64 d, fp32 -> bf16
        #pragma unroll
        for (int it = 0; it < 2; ++it) {
            int s = it * 256 + tid;
            int f = s >> 3, g = s & 7;
            const float* src = w1 + ((size_t)(e * FDIM + f0 + f)) * DIM + d0 + g * 8;
            float4 a = ((const float4*)src)[0];
            float4 b = ((const float4*)src)[1];
            bf16x8 v;
            v[0] = (__bf16)a.x; v[1] = (__bf16)a.y; v[2] = (__bf16)a.z; v[3] = (__bf16)a.w;
            v[4] = (__bf16)b.x; v[5] = (__bf16)b.y; v[6] = (__bf16)b.z; v[7] = (__bf16)b.w;
            *(bf16x8*)(w1s + ((size_t)g * 65 + f) * 8) = v;
        }
        // stage X chunk: 128 t x 64 d (bf16 gathered; pads read zero page)
        {
            const int kg = tid & 7;
            const int r0 = tid >> 3;     // 0..31
            #pragma unroll
            for (int it = 0; it < 4; ++it) {
                int t = it * 32 + r0;
                int r = tb * BT2 + t;
                const __bf16* src = (r < cnt)
                    ? (Xg + ((size_t)(e * CAP + r)) * DIM + d0 + kg * 8)
                    : zp;
                uint4 d = *(const uint4*)src;
                *(uint4*)(xs + ((size_t)kg * 129 + t) * 8) = d;
            }
        }
        __syncthreads();
        // 2 K-steps of 32 per chunk
        #pragma unroll
        for (int ks = 0; ks < 2; ++ks) {
            const int kg = ks * 4 + q;
            bf16x8 af0 = *(const bf16x8*)(w1s + (kg * 65 + fsub + l15) * 8);
            bf16x8 af1 = *(const bf16x8*)(w1s + (kg * 65 + fsub + 16 + l15) * 8);
            #pragma unroll
            for (int tt = 0; tt < 4; ++tt) {
                bf16x8 bfr = *(const bf16x8*)(xs + (kg * 129 + tsub + tt * 16 + l15) * 8);
                acc[0][tt] = __builtin_amdgcn_mfma_f32_16x16x32_bf16(af0, bfr, acc[0][tt], 0, 0, 0);
                acc[1][tt] = __builtin_amdgcn_mfma_f32_16x16x32_bf16(af1, bfr, acc[1][tt], 0, 0, 0);
            }
        }
    }

    // silu then column-sum (pad cols give silu(0)=0)
    float hs[8];
    #pragma unroll
    for (int i = 0; i < 8; ++i) hs[i] = 0.f;
    #pragma unroll
    for (int fa = 0; fa < 2; ++fa)
        #pragma unroll
        for (int tt = 0; tt < 4; ++tt)
            #pragma unroll
            for (int r = 0; r < 4; ++r) {
                float v = acc[fa][tt][r];
                hs[fa * 4 + r] += v / (1.f + __expf(-v));
            }

    // sum over the 16 token-columns held across lanes of each quad
    #pragma unroll
    for (int i = 0; i < 8; ++i) {
        float v = hs[i];
        v += __shfl_xor(v, 1);
        v += __shfl_xor(v, 2);
        v += __shfl_xor(v, 4);
        v += __shfl_xor(v, 8);
        hs[i] = v;
    }
    if (l15 == 0) {
        #pragma unroll
        for (int fa = 0; fa < 2; ++fa)
            #pragma unroll
            for (int r = 0; r < 4; ++r) {
                int row = fsub + fa * 16 + q * 4 + r;
                hred[row][wv >> 1] = hs[fa * 4 + r];
            }
    }
    __syncthreads();
    if (tid < 64)
        atomicAdd(hmean + (size_t)e * FDIM + f0 + tid,
                  (hred[tid][0] + hred[tid][1]) * inv);
}

// ---------------- K3: y_mean[e,d] = h_mean[e,:] . w2[e,d,:]  (fp32) ---------
__global__ __launch_bounds__(256) void k3_ymean(
    const float* __restrict__ w2, const float* __restrict__ hmean,
    const int* __restrict__ counts, float* __restrict__ ymean)
{
    __shared__ float hl[FDIM];           // 8 KB
    const int tid = threadIdx.x;
    const int bid = blockIdx.x;
    const int e   = bid >> 7;
    const int d0  = (bid & 127) * 4;

    {
        const float4* hg = (const float4*)(hmean + (size_t)e * FDIM);
        float4* hl4 = (float4*)hl;
        hl4[tid]       = hg[tid];
        hl4[256 + tid] = hg[256 + tid];
    }
    __syncthreads();

    const int wv = tid >> 6, lane = tid & 63;
    const int d = d0 + wv;
    const float4* wr  = (const float4*)(w2 + ((size_t)e * DIM + d) * FDIM);
    const float4* hl4 = (const float4*)hl;
    float acc = 0.f;
    #pragma unroll
    for (int i = 0; i < 8; ++i) {
        float4 a = wr[i * 64 + lane];
        float4 h = hl4[i * 64 + lane];
        acc += a.x * h.x + a.y * h.y + a.z * h.z + a.w * h.w;
    }
    #pragma unroll
    for (int m = 1; m < 64; m <<= 1) acc += __shfl_xor(acc, m);
    if (lane == 0)
        ymean[e * DIM + d] = (counts[e] > 0) ? acc : 0.f;
}

// ---------------- K4: out[t,:] = w0*y[e0,:] + w1*y[e1,:] --------------------
__global__ __launch_bounds__(256) void k4_combine(
    const int* __restrict__ top_idx, const float* __restrict__ routw,
    const float* __restrict__ ymean, float* __restrict__ out)
{
    const int idx = blockIdx.x * 256 + threadIdx.x;   // float4 index
    const int t = idx >> 7;
    const int c = idx & 127;
    const int i0 = top_idx[t * 2], i1 = top_idx[t * 2 + 1];
    const float w0 = routw[t * 2], w1 = routw[t * 2 + 1];
    float4 a = ((const float4*)(ymean + (size_t)i0 * DIM))[c];
    float4 b = ((const float4*)(ymean + (size_t)i1 * DIM))[c];
    float4 o;
    o.x = w0 * a.x + w1 * b.x;
    o.y = w0 * a.y + w1 * b.y;
    o.z = w0 * a.z + w1 * b.z;
    o.w = w0 * a.w + w1 * b.w;
    ((float4*)out)[idx] = o;
}

extern "C" void kernel_launch(void* const* d_in, const int* in_sizes, int n_in,
                              void* d_out, int out_size, void* d_ws, size_t ws_size,
                              hipStream_t stream)
{
    (void)in_sizes; (void)n_in; (void)out_size; (void)ws_size;
    const float* x  = (const float*)d_in[0];   // [4,512,512]
    const float* gw = (const float*)d_in[1];   // [16,512]
    const float* w1 = (const float*)d_in[2];   // [16,2048,512]
    const float* w2 = (const float*)d_in[3];   // [16,512,2048]
    float* out = (float*)d_out;

    char* ws = (char*)d_ws;
    int*    counts  = (int*)   (ws + WS_COUNTS);
    const __bf16* zp = (const __bf16*)(ws + WS_ZEROPAGE);
    int*    top_idx = (int*)   (ws + WS_TOPIDX);
    float*  routw   = (float*) (ws + WS_ROUTW);
    float*  hmean   = (float*) (ws + WS_HMEAN);
    float*  ymean   = (float*) (ws + WS_YMEAN);
    __bf16* Xg      = (__bf16*)(ws + WS_XG);

    hipMemsetAsync(d_ws, 0, WS_ZERO_BYTES, stream);   // counts + zero page + hmean

    k1_route_gather<<<dim3(NTOK / 16), dim3(256), 0, stream>>>(x, gw, counts, top_idx, routw, Xg);
    k2_expert_ffn  <<<dim3(NTB * 32 * NEXP), dim3(256), 0, stream>>>(w1, Xg, counts, zp, hmean);
    k3_ymean       <<<dim3(NEXP * 128), dim3(256), 0, stream>>>(w2, hmean, counts, ymean);
    k4_combine     <<<dim3(NTOK * DIM / 4 / 256), dim3(256), 0, stream>>>(top_idx, routw, ymean, out);
}